// Round 14
// baseline (172.343 us; speedup 1.0000x reference)
//
#include <hip/hip_runtime.h>
#include <hip/hip_bf16.h>

#define ENC 2048
#define ADIM 512
#define DEC 512
#define NBATCH 128
#define NL 196
#define MTOT (NBATCH * NL)   // 25088
#define NK32 64              // K-steps of 32

typedef __attribute__((ext_vector_type(8))) short short8;
typedef __attribute__((ext_vector_type(4))) float f32x4;
typedef __attribute__((ext_vector_type(4))) unsigned int u32x4;

__device__ __forceinline__ unsigned short f2bf(float f) {
    __hip_bfloat16 h = __float2bfloat16(f);
    union { __hip_bfloat16 h; unsigned short u; } cv; cv.h = h; return cv.u;
}
__device__ __forceinline__ unsigned int f2bf2(float lo, float hi) {
    __hip_bfloat162 h = __float22bfloat162_rn(float2{lo, hi});
    union { __hip_bfloat162 h; unsigned int u; } cv; cv.h = h; return cv.u;
}
__device__ __forceinline__ float bf2f(unsigned short u) {
    union { unsigned int u; float f; } cv; cv.u = ((unsigned int)u) << 16; return cv.f;
}

// async global -> LDS, 16B per lane. lds pointer must be wave-uniform.
__device__ __forceinline__ void load_lds16(const void* g, void* l) {
    __builtin_amdgcn_global_load_lds(
        (const __attribute__((address_space(1))) unsigned int*)g,
        (__attribute__((address_space(3))) unsigned int*)l, 16, 0, 0);
}

// ---------------- kernel 0: feat fp32 -> bf16 (same layout), streaming ----------------
__global__ void cvt_feat_kernel(const float* __restrict__ feat, unsigned short* __restrict__ featb) {
    const size_t total  = (size_t)MTOT * ENC;
    const size_t stride = (size_t)gridDim.x * blockDim.x * 8;
    size_t i = ((size_t)blockIdx.x * blockDim.x + threadIdx.x) * 8;
    for (; i < total; i += stride) {
        f32x4 lo = *(const f32x4*)(feat + i);
        f32x4 hi = *(const f32x4*)(feat + i + 4);
        u32x4 v;
        v.x = f2bf2(lo.x, lo.y); v.y = f2bf2(lo.z, lo.w);
        v.z = f2bf2(hi.x, hi.y); v.w = f2bf2(hi.z, hi.w);
        *(u32x4*)(featb + i) = v;
    }
}

// ---------------- kernel 1: w_ah = hidden @ W_w + W_b  [128 x 512] ----------------
__global__ void wah_kernel(const float* __restrict__ hidden, const float* __restrict__ Ww,
                           const float* __restrict__ Wb, float* __restrict__ wah) {
    __shared__ __align__(16) float hs[DEC];
    const int b = blockIdx.x, a = threadIdx.x;   // block 512 threads
    hs[a] = hidden[b * DEC + a];
    __syncthreads();
    float acc = Wb[a];
    #pragma unroll 4
    for (int d = 0; d < DEC; d += 4) {
        f32x4 h = *(const f32x4*)&hs[d];
        acc += h.x * Ww[(d    ) * ADIM + a];
        acc += h.y * Ww[(d + 1) * ADIM + a];
        acc += h.z * Ww[(d + 2) * ADIM + a];
        acc += h.w * Ww[(d + 3) * ADIM + a];
    }
    wah[b * ADIM + a] = acc;
}

// ---------------- kernel 2: U_w [K=2048][N=512] fp32 -> uwT [N][K] bf16 ----------------
__global__ void transpose_uw(const float* __restrict__ Uw, unsigned short* __restrict__ uwT) {
    __shared__ float t[32][33];
    const int k0 = blockIdx.x * 32, n0 = blockIdx.y * 32;
    const int tx = threadIdx.x, ty = threadIdx.y;   // 32 x 8
    #pragma unroll
    for (int i = 0; i < 4; ++i)
        t[ty + 8 * i][tx] = Uw[(size_t)(k0 + ty + 8 * i) * ADIM + n0 + tx];
    __syncthreads();
    #pragma unroll
    for (int i = 0; i < 4; ++i)
        uwT[(size_t)(n0 + ty + 8 * i) * ENC + k0 + tx] = f2bf(t[tx][ty + 8 * i]);
}

// ---------------- kernel 3: 2-phase pipelined GEMM + tanh + A_w-dot -> partials ------
// Minimum 2-phase recipe (T3 catalog): STAGE(t+1) issued BEFORE COMPUTE(t); single
// vmcnt(0)-drain via __syncthreads at phase end -> stage latency hides under compute.
// The two prior 2-phase failures are fixed: FOUR statically-named 8KB buffers
// (alias-exact, no spurious vmcnt(0) per ds_read — R2/R3 bug) and BK=32 keeps the
// double-buffer at 32KB -> lb(256,4) -> 4 blocks/CU, all 784 blocks co-resident
// (R4's occupancy bug). Both operands bf16 via global_load_lds (R9-proven family).
// Tiles [128 rows][32 k] bf16 = 64B rows (4 x 16B slots); swizzle slot ^= (row>>1)&3:
// reads hit every bank with exactly 2 lanes (free, m136); DMA dest linear,
// source pre-swizzled (rule #21).
__global__ __launch_bounds__(256, 4) void gemm_score_2ph(
    const unsigned short* __restrict__ featb, const unsigned short* __restrict__ uwT,
    const float* __restrict__ Ub, const float* __restrict__ wahb,
    const float* __restrict__ Aw, float* __restrict__ part)
{
    __shared__ __align__(16) unsigned char Ab0[8192];
    __shared__ __align__(16) unsigned char Ab1[8192];
    __shared__ __align__(16) unsigned char Bb0[8192];
    __shared__ __align__(16) unsigned char Bb1[8192];

    const int tid  = threadIdx.x;
    const int lane = tid & 63;
    const int w    = tid >> 6;
    const int wr   = w >> 1, wc = w & 1;
    const int l15  = lane & 15, ldr = lane >> 4;

    // bijective XCD swizzle: 784 blocks = 8 XCD chunks of 98 (nbk fastest -> A-panel shared in L2)
    const int bid  = blockIdx.x;
    const int work = (bid & 7) * 98 + (bid >> 3);
    const int mb   = work >> 2;    // 0..195
    const int nbk  = work & 3;     // 0..3

    // ---- staging sources: wave w rows w*32..+31, 2 chunks of 16 rows (1KB) ----
    // lane -> row (lane>>2) in chunk, 16B slot (lane&3); source k-slot pre-swizzled:
    // s_src = (lane&3) ^ ((row>>1)&3) = (lane&3) ^ ((lane>>3)&3)
    const int srow  = lane >> 2;
    const int sslot = (lane & 3) ^ ((lane >> 3) & 3);
    const unsigned short* aS = featb + (size_t)(mb  * 128 + w * 32 + srow) * ENC + sslot * 8;
    const unsigned short* bS = uwT   + (size_t)(nbk * 128 + w * 32 + srow) * ENC + sslot * 8;

    // ---- fragment read offsets: row r, k-slot ldr ^ ((r>>1)&3); (r>>1)&3 == (l15>>1)&3 ----
    const int rs = (l15 >> 1) & 3;
    int abyte[4], bbyte[4];
    #pragma unroll
    for (int f = 0; f < 4; ++f) {
        const int ra = wr * 64 + f * 16 + l15;
        const int rb = wc * 64 + f * 16 + l15;
        abyte[f] = ra * 64 + ((ldr ^ rs) << 4);
        bbyte[f] = rb * 64 + ((ldr ^ rs) << 4);
    }

    f32x4 acc[4][4];
    #pragma unroll
    for (int i = 0; i < 4; ++i)
        #pragma unroll
        for (int j = 0; j < 4; ++j)
            acc[i][j] = (f32x4){0.f, 0.f, 0.f, 0.f};

#define STAGE(KT, AB, BB) {                                                   \
    _Pragma("unroll")                                                         \
    for (int c = 0; c < 2; ++c) {                                             \
        load_lds16(aS + (size_t)(KT) * 32 + c * 16 * ENC,                     \
                   (AB) + w * 2048 + c * 1024);                               \
        load_lds16(bS + (size_t)(KT) * 32 + c * 16 * ENC,                     \
                   (BB) + w * 2048 + c * 1024);                               \
    }                                                                         \
    __builtin_amdgcn_sched_barrier(0);                                        \
}
#define COMPUTE(AB, BB) {                                                     \
    short8 af[4], bf[4];                                                      \
    _Pragma("unroll")                                                         \
    for (int f = 0; f < 4; ++f) {                                             \
        af[f] = *(const short8*)((AB) + abyte[f]);                            \
        bf[f] = *(const short8*)((BB) + bbyte[f]);                            \
    }                                                                         \
    __builtin_amdgcn_s_setprio(1);                                            \
    _Pragma("unroll")                                                         \
    for (int fm = 0; fm < 4; ++fm)                                            \
        _Pragma("unroll")                                                     \
        for (int fn = 0; fn < 4; ++fn)                                        \
            acc[fm][fn] = __builtin_amdgcn_mfma_f32_16x16x32_bf16(            \
                af[fm], bf[fn], acc[fm][fn], 0, 0, 0);                        \
    __builtin_amdgcn_s_setprio(0);                                            \
}

    STAGE(0, Ab0, Bb0);
    __syncthreads();
    #pragma unroll 1
    for (int kt = 0; kt < NK32; kt += 2) {
        // phase A: stage kt+1 into buf1 (lands under compute), compute buf0
        STAGE(kt + 1, Ab1, Bb1);
        COMPUTE(Ab0, Bb0);
        __syncthreads();                       // drain: buf1 ready, buf0 free
        // phase B
        const int k2 = (kt + 2 < NK32) ? kt + 2 : NK32 - 1;   // last stage is dead, harmless
        STAGE(k2, Ab0, Bb0);
        COMPUTE(Ab1, Bb1);
        __syncthreads();
    }
#undef STAGE
#undef COMPUTE

    // epilogue: score partial = sum_c Aw[c] * tanh(acc + Ub[c] + wah[b][c])
    float ub4[4], aw4[4]; int cidx[4];
    #pragma unroll
    for (int f = 0; f < 4; ++f) {
        const int c = nbk * 128 + wc * 64 + f * 16 + l15;
        cidx[f] = c; ub4[f] = Ub[c]; aw4[f] = Aw[c];
    }
    #pragma unroll
    for (int fm = 0; fm < 4; ++fm) {
        #pragma unroll
        for (int r = 0; r < 4; ++r) {
            const int m = mb * 128 + wr * 64 + fm * 16 + ldr * 4 + r;
            const int b = m / NL;
            const float* wrow = wahb + b * ADIM;
            float s = 0.f;
            #pragma unroll
            for (int f = 0; f < 4; ++f)
                s += aw4[f] * tanhf(acc[fm][f][r] + ub4[f] + wrow[cidx[f]]);
            s += __shfl_xor(s, 1);
            s += __shfl_xor(s, 2);
            s += __shfl_xor(s, 4);
            s += __shfl_xor(s, 8);
            if (l15 == 0) part[(nbk * 2 + wc) * MTOT + m] = s;
        }
    }
}

// ---------------- kernel 4: reduce partials + softmax over L -> alpha ----------------
__global__ void softmax_kernel(const float* __restrict__ part, const float* __restrict__ Ab,
                               float* __restrict__ alpha) {
    const int b = blockIdx.x, t = threadIdx.x;   // 256 threads
    float sv = 0.f;
    if (t < NL) {
        sv = Ab[0];
        #pragma unroll
        for (int p = 0; p < 8; ++p) sv += part[p * MTOT + b * NL + t];
    }
    float v = (t < NL) ? sv : -3.4e38f;
    #pragma unroll
    for (int o = 32; o >= 1; o >>= 1) v = fmaxf(v, __shfl_xor(v, o));
    __shared__ float rm[4], rs[4];
    if ((t & 63) == 0) rm[t >> 6] = v;
    __syncthreads();
    const float bm = fmaxf(fmaxf(rm[0], rm[1]), fmaxf(rm[2], rm[3]));
    const float e = (t < NL) ? expf(sv - bm) : 0.f;
    float s = e;
    #pragma unroll
    for (int o = 32; o >= 1; o >>= 1) s += __shfl_xor(s, o);
    if ((t & 63) == 0) rs[t >> 6] = s;
    __syncthreads();
    const float bs = rs[0] + rs[1] + rs[2] + rs[3];
    if (t < NL) alpha[b * NL + t] = e / bs;
}

// ---------------- kernel 5: context from bf16 featb ----------------
__global__ void context_bf16_kernel(const unsigned short* __restrict__ featb,
                                    const float* __restrict__ alpha, float* __restrict__ ctx) {
    __shared__ float al[NL];
    const int b = blockIdx.x, chunk = blockIdx.y, t = threadIdx.x;  // 128 threads
    for (int i = t; i < NL; i += 128) al[i] = alpha[b * NL + i];
    __syncthreads();
    const int e0 = chunk * 1024 + t * 8;
    const unsigned short* fp = featb + (size_t)b * NL * ENC + e0;
    float a0=0.f,a1=0.f,a2=0.f,a3=0.f,a4=0.f,a5=0.f,a6=0.f,a7=0.f;
    for (int l = 0; l < NL; ++l) {
        short8 v = *(const short8*)(fp + (size_t)l * ENC);
        const float sc = al[l];
        a0 += sc * bf2f((unsigned short)v[0]);
        a1 += sc * bf2f((unsigned short)v[1]);
        a2 += sc * bf2f((unsigned short)v[2]);
        a3 += sc * bf2f((unsigned short)v[3]);
        a4 += sc * bf2f((unsigned short)v[4]);
        a5 += sc * bf2f((unsigned short)v[5]);
        a6 += sc * bf2f((unsigned short)v[6]);
        a7 += sc * bf2f((unsigned short)v[7]);
    }
    float* cp = ctx + (size_t)b * ENC + e0;
    f32x4 r0 = (f32x4){a0, a1, a2, a3};
    f32x4 r1 = (f32x4){a4, a5, a6, a7};
    *(f32x4*)cp = r0;
    *(f32x4*)(cp + 4) = r1;
}

extern "C" void kernel_launch(void* const* d_in, const int* in_sizes, int n_in,
                              void* d_out, int out_size, void* d_ws, size_t ws_size,
                              hipStream_t stream) {
    const float* feat   = (const float*)d_in[0];
    const float* hidden = (const float*)d_in[1];
    const float* Uw     = (const float*)d_in[2];
    const float* Ub     = (const float*)d_in[3];
    const float* Ww     = (const float*)d_in[4];
    const float* Wb     = (const float*)d_in[5];
    const float* Aw     = (const float*)d_in[6];
    const float* Ab     = (const float*)d_in[7];

    float* out   = (float*)d_out;
    float* alpha = out;              // [128*196]
    float* ctx   = out + MTOT;       // [128*2048]

    const size_t FEATB_BYTES = (size_t)MTOT * ENC * 2;           // 102,760,448

    char* ws = (char*)d_ws;
    unsigned short* featb = (unsigned short*)ws;
    float*          wahb  = (float*)(ws + FEATB_BYTES);
    unsigned short* uwT   = (unsigned short*)(ws + FEATB_BYTES + 262144);
    float*          partb = (float*)(ws + FEATB_BYTES + 262144 + 2097152);

    cvt_feat_kernel<<<dim3(2048), dim3(256), 0, stream>>>(feat, featb);
    wah_kernel<<<dim3(128), dim3(512), 0, stream>>>(hidden, Ww, Wb, wahb);
    transpose_uw<<<dim3(64, 16), dim3(32, 8), 0, stream>>>(Uw, uwT);
    gemm_score_2ph<<<dim3(784), dim3(256), 0, stream>>>(featb, uwT, Ub, wahb, Aw, partb);
    softmax_kernel<<<dim3(128), dim3(256), 0, stream>>>(partb, Ab, alpha);
    context_bf16_kernel<<<dim3(128, 2), dim3(128), 0, stream>>>(featb, alpha, ctx);
}

// Round 15
// 165.339 us; speedup vs baseline: 1.0424x; 1.0424x over previous
//
#include <hip/hip_runtime.h>
#include <hip/hip_bf16.h>

#define ENC 2048
#define ADIM 512
#define DEC 512
#define NBATCH 128
#define NL 196
#define MTOT (NBATCH * NL)   // 25088
#define NKT 32               // K-steps of 64

typedef __attribute__((ext_vector_type(8))) short short8;
typedef __attribute__((ext_vector_type(4))) float f32x4;
typedef __attribute__((ext_vector_type(4))) unsigned int u32x4;

__device__ __forceinline__ unsigned short f2bf(float f) {
    __hip_bfloat16 h = __float2bfloat16(f);
    union { __hip_bfloat16 h; unsigned short u; } cv; cv.h = h; return cv.u;
}
__device__ __forceinline__ unsigned int f2bf2(float lo, float hi) {
    __hip_bfloat162 h = __float22bfloat162_rn(float2{lo, hi});
    union { __hip_bfloat162 h; unsigned int u; } cv; cv.h = h; return cv.u;
}
__device__ __forceinline__ float bf2f(unsigned short u) {
    union { unsigned int u; float f; } cv; cv.u = ((unsigned int)u) << 16; return cv.f;
}

// async global -> LDS, 16B per lane. lds pointer must be wave-uniform.
__device__ __forceinline__ void load_lds16(const void* g, void* l) {
    __builtin_amdgcn_global_load_lds(
        (const __attribute__((address_space(1))) unsigned int*)g,
        (__attribute__((address_space(3))) unsigned int*)l, 16, 0, 0);
}

// ---------------- kernel 0: feat fp32 -> bf16 (same layout), streaming ----------------
__global__ void cvt_feat_kernel(const float* __restrict__ feat, unsigned short* __restrict__ featb) {
    const size_t total  = (size_t)MTOT * ENC;           // 51,380,224 (multiple of 8)
    const size_t stride = (size_t)gridDim.x * blockDim.x * 8;
    size_t i = ((size_t)blockIdx.x * blockDim.x + threadIdx.x) * 8;
    for (; i < total; i += stride) {
        f32x4 lo = *(const f32x4*)(feat + i);
        f32x4 hi = *(const f32x4*)(feat + i + 4);
        u32x4 v;
        v.x = f2bf2(lo.x, lo.y); v.y = f2bf2(lo.z, lo.w);
        v.z = f2bf2(hi.x, hi.y); v.w = f2bf2(hi.z, hi.w);
        *(u32x4*)(featb + i) = v;
    }
}

// ---------------- kernel 1: w_ah = hidden @ W_w + W_b  [128 x 512] ----------------
__global__ void wah_kernel(const float* __restrict__ hidden, const float* __restrict__ Ww,
                           const float* __restrict__ Wb, float* __restrict__ wah) {
    __shared__ __align__(16) float hs[DEC];
    const int b = blockIdx.x, a = threadIdx.x;   // block 512 threads
    hs[a] = hidden[b * DEC + a];
    __syncthreads();
    float acc = Wb[a];
    #pragma unroll 4
    for (int d = 0; d < DEC; d += 4) {
        f32x4 h = *(const f32x4*)&hs[d];
        acc += h.x * Ww[(d    ) * ADIM + a];
        acc += h.y * Ww[(d + 1) * ADIM + a];
        acc += h.z * Ww[(d + 2) * ADIM + a];
        acc += h.w * Ww[(d + 3) * ADIM + a];
    }
    wah[b * ADIM + a] = acc;
}

// ---------------- kernel 2: U_w [K=2048][N=512] fp32 -> uwT [N][K] bf16 ----------------
__global__ void transpose_uw(const float* __restrict__ Uw, unsigned short* __restrict__ uwT) {
    __shared__ float t[32][33];
    const int k0 = blockIdx.x * 32, n0 = blockIdx.y * 32;
    const int tx = threadIdx.x, ty = threadIdx.y;   // 32 x 8
    #pragma unroll
    for (int i = 0; i < 4; ++i)
        t[ty + 8 * i][tx] = Uw[(size_t)(k0 + ty + 8 * i) * ADIM + n0 + tx];
    __syncthreads();
    #pragma unroll
    for (int i = 0; i < 4; ++i)
        uwT[(size_t)(n0 + ty + 8 * i) * ENC + k0 + tx] = f2bf(t[tx][ty + 8 * i]);
}

// ---------------- kernel 3 (fast): m97-structure GEMM, both operands bf16 DMA ----------------
// 128x128 tile, BK=64, 4 waves 2x2 (wave tile 64x64), single-buffer LDS (32KB),
// 2 barriers/K-step. A=featb, B=uwT via global_load_lds w16, pre-swizzled source
// (slot ^= row&7), linear dest, swizzled read. 0 bank conflicts (R7-measured).
// launch_bounds(256,4) -> 4 blocks/CU resident -> all 784 blocks co-resident
// (capacity 1024): single dispatch round, no tail. Empirical optimum (R9: 165.8us;
// eight alternative structures R2-R14 all slower).
__global__ __launch_bounds__(256, 4) void gemm_score_bf16(
    const unsigned short* __restrict__ featb, const unsigned short* __restrict__ uwT,
    const float* __restrict__ Ub, const float* __restrict__ wahb,
    const float* __restrict__ Aw, float* __restrict__ part)
{
    __shared__ __align__(16) unsigned char As[16384];   // [128][64] bf16 swizzled
    __shared__ __align__(16) unsigned char Bs[16384];   // [128][64] bf16 swizzled

    const int tid  = threadIdx.x;
    const int lane = tid & 63;
    const int w    = tid >> 6;
    const int wr   = w >> 1, wc = w & 1;
    const int l15  = lane & 15, ldr = lane >> 4;

    // bijective XCD swizzle: 784 blocks = 8 XCD chunks of 98 (nbk fastest -> A-panel shared in L2)
    const int bid  = blockIdx.x;
    const int work = (bid & 7) * 98 + (bid >> 3);
    const int mb   = work >> 2;    // 0..195
    const int nbk  = work & 3;     // 0..3

    // ---- DMA sources: wave w stages rows w*32..+31 of A and of B (4 chunks of 8 rows) ----
    // lane -> row (lane>>3) within chunk, 16B slot (lane&7); source k-slot pre-swizzled ^ (row&7)
    const int swz = ((lane & 7) ^ ((lane >> 3) & 7)) << 3;   // in bf16 elems (8 per 16B slot)
    const unsigned short* aS = featb + (size_t)(mb  * 128 + w * 32 + (lane >> 3)) * ENC + swz;
    const unsigned short* bS = uwT   + (size_t)(nbk * 128 + w * 32 + (lane >> 3)) * ENC + swz;

    // ---- fragment read offsets: row r, k-slot q=ks*4+ldr, byte = r*128 + ((q^(r&7))<<4) ----
    int abyte[4][2], bbyte[4][2];
    #pragma unroll
    for (int f = 0; f < 4; ++f) {
        const int ra = wr * 64 + f * 16 + l15;
        const int rb = wc * 64 + f * 16 + l15;
        #pragma unroll
        for (int ks = 0; ks < 2; ++ks) {
            abyte[f][ks] = ra * 128 + (((ks * 4 + ldr) ^ (ra & 7)) << 4);
            bbyte[f][ks] = rb * 128 + (((ks * 4 + ldr) ^ (rb & 7)) << 4);
        }
    }

    f32x4 acc[4][4];
    #pragma unroll
    for (int i = 0; i < 4; ++i)
        #pragma unroll
        for (int j = 0; j < 4; ++j)
            acc[i][j] = (f32x4){0.f, 0.f, 0.f, 0.f};

    #pragma unroll 1
    for (int kt = 0; kt < NKT; ++kt) {
        #pragma unroll
        for (int c = 0; c < 4; ++c)
            load_lds16(aS + (size_t)kt * 64 + c * 8 * ENC, As + w * 4096 + c * 1024);
        #pragma unroll
        for (int c = 0; c < 4; ++c)
            load_lds16(bS + (size_t)kt * 64 + c * 8 * ENC, Bs + w * 4096 + c * 1024);
        __syncthreads();   // drains DMA: tile ready

        #pragma unroll
        for (int ks = 0; ks < 2; ++ks) {
            short8 af[4], bf[4];
            #pragma unroll
            for (int f = 0; f < 4; ++f) {
                af[f] = *(const short8*)(As + abyte[f][ks]);
                bf[f] = *(const short8*)(Bs + bbyte[f][ks]);
            }
            #pragma unroll
            for (int fm = 0; fm < 4; ++fm)
                #pragma unroll
                for (int fn = 0; fn < 4; ++fn)
                    acc[fm][fn] = __builtin_amdgcn_mfma_f32_16x16x32_bf16(
                        af[fm], bf[fn], acc[fm][fn], 0, 0, 0);
        }
        __syncthreads();   // reads done: next stage may overwrite
    }

    // epilogue: score partial = sum_c Aw[c] * tanh(acc + Ub[c] + wah[b][c])
    float ub4[4], aw4[4]; int cidx[4];
    #pragma unroll
    for (int f = 0; f < 4; ++f) {
        const int c = nbk * 128 + wc * 64 + f * 16 + l15;
        cidx[f] = c; ub4[f] = Ub[c]; aw4[f] = Aw[c];
    }
    #pragma unroll
    for (int fm = 0; fm < 4; ++fm) {
        #pragma unroll
        for (int r = 0; r < 4; ++r) {
            const int m = mb * 128 + wr * 64 + fm * 16 + ldr * 4 + r;
            const int b = m / NL;
            const float* wrow = wahb + b * ADIM;
            float s = 0.f;
            #pragma unroll
            for (int f = 0; f < 4; ++f)
                s += aw4[f] * tanhf(acc[fm][f][r] + ub4[f] + wrow[cidx[f]]);
            s += __shfl_xor(s, 1);
            s += __shfl_xor(s, 2);
            s += __shfl_xor(s, 4);
            s += __shfl_xor(s, 8);
            if (l15 == 0) part[(nbk * 2 + wc) * MTOT + m] = s;
        }
    }
}

// ---------------- kernel 3 (fallback, ws too small): R6 structure, fp32 A ----------------
__global__ __launch_bounds__(256, 4) void gemm_score_fp32(
    const float* __restrict__ feat, const unsigned short* __restrict__ uwT,
    const float* __restrict__ Ub, const float* __restrict__ wahb,
    const float* __restrict__ Aw, float* __restrict__ part)
{
    __shared__ __align__(16) unsigned char As[8192];
    __shared__ __align__(16) unsigned char Bs[16384];

    const int tid  = threadIdx.x;
    const int lane = tid & 63;
    const int w    = tid >> 6;
    const int l15  = lane & 15, ldr = lane >> 4;

    const int bid  = blockIdx.x;
    const int work = (bid & 7) * 196 + (bid >> 3);
    const int mb   = work >> 2;
    const int nbk  = work & 3;

    const int r_ = tid >> 2, kq = tid & 3;
    const float* aSrc = feat + (size_t)(mb * 64 + r_) * ENC + kq * 16;
    const int wA0 = r_ * 128 + (((kq * 2    ) ^ (r_ & 7)) << 4);
    const int wA1 = r_ * 128 + (((kq * 2 + 1) ^ (r_ & 7)) << 4);

    const unsigned short* bSrc = uwT
        + (size_t)(nbk * 128 + w * 32 + (lane >> 3)) * ENC
        + (((lane & 7) ^ ((lane >> 3) & 7)) << 3);

    int abyte[4][2], bbyte[2][2];
    #pragma unroll
    for (int ks = 0; ks < 2; ++ks) {
        const int sl = ((ks * 4 + ldr) ^ (l15 & 7)) << 4;
        #pragma unroll
        for (int f = 0; f < 4; ++f)
            abyte[f][ks] = (f * 16 + l15) * 128 + sl;
        #pragma unroll
        for (int g = 0; g < 2; ++g)
            bbyte[g][ks] = (w * 32 + g * 16 + l15) * 128 + sl;
    }

    f32x4 acc[4][2];
    #pragma unroll
    for (int i = 0; i < 4; ++i)
        #pragma unroll
        for (int j = 0; j < 2; ++j)
            acc[i][j] = (f32x4){0.f, 0.f, 0.f, 0.f};

    #pragma unroll 1
    for (int kt = 0; kt < NKT; ++kt) {
        const f32x4* p = (const f32x4*)(aSrc + (size_t)kt * 64);
        f32x4 a0 = p[0], a1 = p[1], a2 = p[2], a3 = p[3];
        #pragma unroll
        for (int c = 0; c < 4; ++c)
            load_lds16(bSrc + (size_t)kt * 64 + c * 8 * ENC, Bs + w * 4096 + c * 1024);
        u32x4 w0, w1;
        w0.x = f2bf2(a0.x, a0.y); w0.y = f2bf2(a0.z, a0.w);
        w0.z = f2bf2(a1.x, a1.y); w0.w = f2bf2(a1.z, a1.w);
        w1.x = f2bf2(a2.x, a2.y); w1.y = f2bf2(a2.z, a2.w);
        w1.z = f2bf2(a3.x, a3.y); w1.w = f2bf2(a3.z, a3.w);
        *(u32x4*)(As + wA0) = w0;
        *(u32x4*)(As + wA1) = w1;
        __syncthreads();

        #pragma unroll
        for (int ks = 0; ks < 2; ++ks) {
            short8 af[4], bf[2];
            #pragma unroll
            for (int f = 0; f < 4; ++f) af[f] = *(const short8*)(As + abyte[f][ks]);
            #pragma unroll
            for (int g = 0; g < 2; ++g) bf[g] = *(const short8*)(Bs + bbyte[g][ks]);
            #pragma unroll
            for (int fm = 0; fm < 4; ++fm)
                #pragma unroll
                for (int g = 0; g < 2; ++g)
                    acc[fm][g] = __builtin_amdgcn_mfma_f32_16x16x32_bf16(
                        af[fm], bf[g], acc[fm][g], 0, 0, 0);
        }
        __syncthreads();
    }

    float ub2[2], aw2[2]; int cidx[2];
    #pragma unroll
    for (int g = 0; g < 2; ++g) {
        const int c = nbk * 128 + w * 32 + g * 16 + l15;
        cidx[g] = c; ub2[g] = Ub[c]; aw2[g] = Aw[c];
    }
    #pragma unroll
    for (int fm = 0; fm < 4; ++fm) {
        #pragma unroll
        for (int r = 0; r < 4; ++r) {
            const int m = mb * 64 + fm * 16 + ldr * 4 + r;
            const int b = m / NL;
            const float* wrow = wahb + b * ADIM;
            #pragma unroll
            for (int g = 0; g < 2; ++g) {
                float s = aw2[g] * tanhf(acc[fm][g][r] + ub2[g] + wrow[cidx[g]]);
                s += __shfl_xor(s, 1);
                s += __shfl_xor(s, 2);
                s += __shfl_xor(s, 4);
                s += __shfl_xor(s, 8);
                if (l15 == 0) part[(nbk * 8 + w * 2 + g) * MTOT + m] = s;
            }
        }
    }
}

// ---------------- kernel 4: reduce partials + softmax over L -> alpha ----------------
__global__ void softmax_kernel(const float* __restrict__ part, const float* __restrict__ Ab,
                               float* __restrict__ alpha, int npart) {
    const int b = blockIdx.x, t = threadIdx.x;   // 256 threads
    float sv = 0.f;
    if (t < NL) {
        sv = Ab[0];
        for (int p = 0; p < npart; ++p) sv += part[p * MTOT + b * NL + t];
    }
    float v = (t < NL) ? sv : -3.4e38f;
    #pragma unroll
    for (int o = 32; o >= 1; o >>= 1) v = fmaxf(v, __shfl_xor(v, o));
    __shared__ float rm[4], rs[4];
    if ((t & 63) == 0) rm[t >> 6] = v;
    __syncthreads();
    const float bm = fmaxf(fmaxf(rm[0], rm[1]), fmaxf(rm[2], rm[3]));
    const float e = (t < NL) ? expf(sv - bm) : 0.f;
    float s = e;
    #pragma unroll
    for (int o = 32; o >= 1; o >>= 1) s += __shfl_xor(s, o);
    if ((t & 63) == 0) rs[t >> 6] = s;
    __syncthreads();
    const float bs = rs[0] + rs[1] + rs[2] + rs[3];
    if (t < NL) alpha[b * NL + t] = e / bs;
}

// ---------------- kernel 5a: context from bf16 featb ----------------
__global__ void context_bf16_kernel(const unsigned short* __restrict__ featb,
                                    const float* __restrict__ alpha, float* __restrict__ ctx) {
    __shared__ float al[NL];
    const int b = blockIdx.x, chunk = blockIdx.y, t = threadIdx.x;  // 128 threads
    for (int i = t; i < NL; i += 128) al[i] = alpha[b * NL + i];
    __syncthreads();
    const int e0 = chunk * 1024 + t * 8;
    const unsigned short* fp = featb + (size_t)b * NL * ENC + e0;
    float a0=0.f,a1=0.f,a2=0.f,a3=0.f,a4=0.f,a5=0.f,a6=0.f,a7=0.f;
    for (int l = 0; l < NL; ++l) {
        short8 v = *(const short8*)(fp + (size_t)l * ENC);
        const float sc = al[l];
        a0 += sc * bf2f((unsigned short)v[0]);
        a1 += sc * bf2f((unsigned short)v[1]);
        a2 += sc * bf2f((unsigned short)v[2]);
        a3 += sc * bf2f((unsigned short)v[3]);
        a4 += sc * bf2f((unsigned short)v[4]);
        a5 += sc * bf2f((unsigned short)v[5]);
        a6 += sc * bf2f((unsigned short)v[6]);
        a7 += sc * bf2f((unsigned short)v[7]);
    }
    float* cp = ctx + (size_t)b * ENC + e0;
    f32x4 r0 = (f32x4){a0, a1, a2, a3};
    f32x4 r1 = (f32x4){a4, a5, a6, a7};
    *(f32x4*)cp = r0;
    *(f32x4*)(cp + 4) = r1;
}

// ---------------- kernel 5b: context from fp32 feat (fallback) ----------------
__global__ void context_kernel(const float* __restrict__ feat, const float* __restrict__ alpha,
                               float* __restrict__ ctx) {
    __shared__ float al[NL];
    const int b = blockIdx.x, chunk = blockIdx.y, t = threadIdx.x;  // 128 threads
    for (int i = t; i < NL; i += 128) al[i] = alpha[b * NL + i];
    __syncthreads();
    const int e0 = chunk * 512 + t * 4;
    const float* fp = feat + (size_t)b * NL * ENC + e0;
    f32x4 acc0 = (f32x4){0.f, 0.f, 0.f, 0.f};
    f32x4 acc1 = (f32x4){0.f, 0.f, 0.f, 0.f};
    #pragma unroll 2
    for (int l = 0; l < NL; l += 2) {
        f32x4 f0 = *(const f32x4*)(fp + (size_t)l * ENC);
        f32x4 f1 = *(const f32x4*)(fp + (size_t)(l + 1) * ENC);
        acc0 += al[l] * f0;
        acc1 += al[l + 1] * f1;
    }
    f32x4 rsum = acc0 + acc1;
    *(f32x4*)(ctx + (size_t)b * ENC + e0) = rsum;
}

extern "C" void kernel_launch(void* const* d_in, const int* in_sizes, int n_in,
                              void* d_out, int out_size, void* d_ws, size_t ws_size,
                              hipStream_t stream) {
    const float* feat   = (const float*)d_in[0];
    const float* hidden = (const float*)d_in[1];
    const float* Uw     = (const float*)d_in[2];
    const float* Ub     = (const float*)d_in[3];
    const float* Ww     = (const float*)d_in[4];
    const float* Wb     = (const float*)d_in[5];
    const float* Aw     = (const float*)d_in[6];
    const float* Ab     = (const float*)d_in[7];

    float* out   = (float*)d_out;
    float* alpha = out;              // [128*196]
    float* ctx   = out + MTOT;       // [128*2048]

    const size_t FEATB_BYTES = (size_t)MTOT * ENC * 2;           // 102,760,448
    const size_t BIG_NEED    = FEATB_BYTES + 262144 + 2097152 + (size_t)8 * MTOT * 4;

    char* ws = (char*)d_ws;

    if (ws_size >= BIG_NEED) {
        unsigned short* featb = (unsigned short*)ws;
        float*          wahb  = (float*)(ws + FEATB_BYTES);
        unsigned short* uwT   = (unsigned short*)(ws + FEATB_BYTES + 262144);
        float*          partb = (float*)(ws + FEATB_BYTES + 262144 + 2097152);

        cvt_feat_kernel<<<dim3(2048), dim3(256), 0, stream>>>(feat, featb);
        wah_kernel<<<dim3(128), dim3(512), 0, stream>>>(hidden, Ww, Wb, wahb);
        transpose_uw<<<dim3(64, 16), dim3(32, 8), 0, stream>>>(Uw, uwT);
        gemm_score_bf16<<<dim3(784), dim3(256), 0, stream>>>(featb, uwT, Ub, wahb, Aw, partb);
        softmax_kernel<<<dim3(128), dim3(256), 0, stream>>>(partb, Ab, alpha, 8);
        context_bf16_kernel<<<dim3(128, 2), dim3(128), 0, stream>>>(featb, alpha, ctx);
    } else {
        float*          wahb  = (float*)ws;
        unsigned short* uwT   = (unsigned short*)(ws + 262144);
        float*          partb = (float*)(ws + 262144 + 2097152);

        wah_kernel<<<dim3(128), dim3(512), 0, stream>>>(hidden, Ww, Wb, wahb);
        transpose_uw<<<dim3(64, 16), dim3(32, 8), 0, stream>>>(Uw, uwT);
        gemm_score_fp32<<<dim3(1568), dim3(256), 0, stream>>>(feat, uwT, Ub, wahb, Aw, partb);
        softmax_kernel<<<dim3(128), dim3(256), 0, stream>>>(partb, Ab, alpha, 32);
        context_kernel<<<dim3(128, 4), dim3(128), 0, stream>>>(feat, alpha, ctx);
    }
}